// Round 12
// baseline (287.487 us; speedup 1.0000x reference)
//
#include <hip/hip_runtime.h>
#include <cstdint>

#define HDIM 128
#define EPSV 1e-5f
#define SCAN_BLK 1024

typedef short  short8 __attribute__((ext_vector_type(8)));
typedef __bf16 bf16x8 __attribute__((ext_vector_type(8)));
typedef float  f32x4  __attribute__((ext_vector_type(4)));

__device__ __forceinline__ unsigned short f2bf_rne(float x) {
    unsigned int u = __float_as_uint(x);
    return (unsigned short)((u + 0x7FFFu + ((u >> 16) & 1u)) >> 16);
}
__device__ __forceinline__ float bf_lo(unsigned int u) { return __uint_as_float(u << 16); }
__device__ __forceinline__ float bf_hi(unsigned int u) { return __uint_as_float(u & 0xFFFF0000u); }

// ================= CSR build =================
__global__ void k_hist(const int* __restrict__ ei, int* __restrict__ cnt, int E) {
    int e = blockIdx.x * blockDim.x + threadIdx.x;
    if (e < E) atomicAdd(&cnt[ei[E + e]], 1);
}

__global__ __launch_bounds__(256) void k_scan1(const int* __restrict__ cnt,
                                               int* __restrict__ rowptr,
                                               int* __restrict__ bsum, int N) {
    __shared__ int lds[256];
    int b = blockIdx.x, t = threadIdx.x;
    int base = b * SCAN_BLK;
    int v[4]; int s = 0;
    #pragma unroll
    for (int c = 0; c < 4; ++c) { int i = base + t * 4 + c; v[c] = (i < N) ? cnt[i] : 0; s += v[c]; }
    lds[t] = s; __syncthreads();
    for (int off = 1; off < 256; off <<= 1) {
        int x = 0;
        if (t >= off) x = lds[t - off];
        __syncthreads();
        if (t >= off) lds[t] += x;
        __syncthreads();
    }
    int excl = (t > 0) ? lds[t - 1] : 0;
    if (t == 255) bsum[b] = lds[255];
    int run = excl;
    #pragma unroll
    for (int c = 0; c < 4; ++c) { int i = base + t * 4 + c; if (i < N) rowptr[i] = run; run += v[c]; }
}

__global__ void k_scan3(int* __restrict__ rowptr, const int* __restrict__ bsum, int N, int E) {
    int i = blockIdx.x * blockDim.x + threadIdx.x;
    if (i < N) {
        int nb = i / SCAN_BLK;
        int off = 0;
        for (int k = 0; k < nb; ++k) off += bsum[k];
        rowptr[i] += off;
    }
    if (i == 0) rowptr[N] = E;
}

__global__ void k_fill(const int* __restrict__ ei, const int* __restrict__ rowptr,
                       int* __restrict__ cnt, int* __restrict__ col, int E) {
    int e = blockIdx.x * blockDim.x + threadIdx.x;
    if (e < E) {
        int d = ei[E + e];
        int p = atomicSub(&cnt[d], 1) - 1;
        col[rowptr[d] + p] = ei[e];
    }
}

// ================= fp32 -> packed bf16 plane (also zeroes cnt) =================
__global__ void k_tobf(const float* __restrict__ src, unsigned int* __restrict__ dst, size_t n2,
                       int* __restrict__ cnt, int N) {
    size_t i = (size_t)blockIdx.x * blockDim.x + threadIdx.x;
    if (i < (size_t)N) cnt[i] = 0;
    if (i >= n2) return;
    float2 v = ((const float2*)src)[i];
    dst[i] = ((unsigned int)f2bf_rne(v.y) << 16) | f2bf_rne(v.x);
}

// ================= W pre-pack into MFMA B-fragment order (hi/lo split); zeroes stats =================
__global__ void k_pack_all(const float* __restrict__ Wl0, const float* __restrict__ Wr0,
                           const float* __restrict__ Wl1, const float* __restrict__ Wr1,
                           const float* __restrict__ Wlo, const float* __restrict__ Wro,
                           unsigned short* __restrict__ pk0, unsigned short* __restrict__ pk1,
                           unsigned short* __restrict__ pko, float* __restrict__ stats01, int C) {
    if (blockIdx.y == 0 && blockIdx.x == 0) {
        stats01[threadIdx.x] = 0.f;
        stats01[256 + threadIdx.x] = 0.f;
    }
    const float* W; unsigned short* WH; unsigned short* WL; int FOUT, NT;
    switch (blockIdx.y) {
        case 0:  W = Wl0; WH = pk0;          WL = pk0 + 16384; FOUT = 128; NT = 8; break;
        case 1:  W = Wr0; WH = pk0 + 32768;  WL = pk0 + 49152; FOUT = 128; NT = 8; break;
        case 2:  W = Wl1; WH = pk1;          WL = pk1 + 16384; FOUT = 128; NT = 8; break;
        case 3:  W = Wr1; WH = pk1 + 32768;  WL = pk1 + 49152; FOUT = 128; NT = 8; break;
        case 4:  W = Wlo; WH = pko;          WL = pko + 6144;  FOUT = C;   NT = 3; break;
        default: W = Wro; WH = pko + 12288;  WL = pko + 18432; FOUT = C;   NT = 3; break;
    }
    int tid = blockIdx.x * 256 + threadIdx.x;
    if (tid >= NT * 2048) return;
    int e = tid & 7, lane = (tid >> 3) & 63, kk = (tid >> 9) & 3, ct = tid >> 11;
    int j = ct * 16 + (lane & 15);
    int k = kk * 32 + (lane >> 4) * 8 + e;
    float v = (j < FOUT) ? W[k * FOUT + j] : 0.0f;
    unsigned short h = f2bf_rne(v);
    float hf = __uint_as_float((unsigned int)h << 16);
    unsigned short l = f2bf_rne(v - hf);
    WH[tid] = h; WL[tid] = l;
}

// ================= fully fused SAGE layer =================
// Per block (32 rows, 512 thr = 8 waves):
//   phase 1: gather neighbor means (stride-4 edges per 16-lane group) -> LDS mat0
//            + stage self features; optional relu(BN(v)) on both paths -> LDS mat1
//   phase 2: MFMA vs pre-packed split-bf16 W (wave = column tile)
//   phase 3: write pre-BN bf16 (outh), or fused log_softmax fp32 (outf).
template<int NT, bool BN, bool SOFTMAX>
__global__ __launch_bounds__(512) void k_sage_fused(
    const int* __restrict__ rowptr, const int* __restrict__ col,
    const unsigned int* __restrict__ featb,
    const float* __restrict__ stats, const float* __restrict__ gam, const float* __restrict__ bet,
    const unsigned short* __restrict__ pk, const float* __restrict__ bias,
    float* __restrict__ outf, unsigned short* __restrict__ outh,
    int N, int FOUT, float invN) {
    __shared__ __align__(16) char smem[16384];   // [mat][32 rows][16 slots * 16B]
    int tid = threadIdx.x;
    int row0 = blockIdx.x * 32;
    int lane = tid & 63;
    int wv = tid >> 6;            // 0..7
    int g4 = lane >> 4;           // edge group 0..3
    int lo = lane & 15;           // 16B chunk / slot

    // BN coefficients for this thread's 8 columns (cols lo*8 .. lo*8+7)
    float bnA[8], bnC[8];
    if (BN) {
        #pragma unroll
        for (int c = 0; c < 8; ++c) {
            int j = lo * 8 + c;
            float mu = stats[j] * invN;
            float var = stats[HDIM + j] * invN - mu * mu;
            float aa = gam[j] * rsqrtf(var + EPSV);
            bnA[c] = aa; bnC[c] = bet[j] - mu * aa;
        }
    }

    // ---- phase 1a: gather (4 nodes per wave) -> LDS mat0 ----
    #pragma unroll
    for (int nn = 0; nn < 4; ++nn) {
        int row = wv * 4 + nn;
        int node = row0 + row;
        float a[8] = {0,0,0,0,0,0,0,0};
        int beg = 0, end = 0;
        if (node < N) { beg = rowptr[node]; end = rowptr[node + 1]; }
        for (int e = beg + g4; e < end; e += 4) {
            const uint4 v = *(const uint4*)(featb + (size_t)col[e] * 64 + lo * 4);
            float t0 = bf_lo(v.x), t1 = bf_hi(v.x), t2 = bf_lo(v.y), t3 = bf_hi(v.y);
            float t4 = bf_lo(v.z), t5 = bf_hi(v.z), t6 = bf_lo(v.w), t7 = bf_hi(v.w);
            if (BN) {
                t0 = fmaxf(bnA[0]*t0 + bnC[0], 0.f); t1 = fmaxf(bnA[1]*t1 + bnC[1], 0.f);
                t2 = fmaxf(bnA[2]*t2 + bnC[2], 0.f); t3 = fmaxf(bnA[3]*t3 + bnC[3], 0.f);
                t4 = fmaxf(bnA[4]*t4 + bnC[4], 0.f); t5 = fmaxf(bnA[5]*t5 + bnC[5], 0.f);
                t6 = fmaxf(bnA[6]*t6 + bnC[6], 0.f); t7 = fmaxf(bnA[7]*t7 + bnC[7], 0.f);
            }
            a[0] += t0; a[1] += t1; a[2] += t2; a[3] += t3;
            a[4] += t4; a[5] += t5; a[6] += t6; a[7] += t7;
        }
        #pragma unroll
        for (int i = 0; i < 8; ++i) {
            a[i] += __shfl_xor(a[i], 16);
            a[i] += __shfl_xor(a[i], 32);
        }
        if (g4 == 0) {
            int deg = end - beg;
            float inv = (deg > 0) ? 1.0f / (float)deg : 0.0f;
            uint4 o;
            o.x = ((unsigned int)f2bf_rne(a[1] * inv) << 16) | f2bf_rne(a[0] * inv);
            o.y = ((unsigned int)f2bf_rne(a[3] * inv) << 16) | f2bf_rne(a[2] * inv);
            o.z = ((unsigned int)f2bf_rne(a[5] * inv) << 16) | f2bf_rne(a[4] * inv);
            o.w = ((unsigned int)f2bf_rne(a[7] * inv) << 16) | f2bf_rne(a[6] * inv);
            int sp = lo ^ (row & 15);
            *(uint4*)(smem + (0 * 32 + row) * 256 + sp * 16) = o;
        }
    }

    // ---- phase 1b: self features -> LDS mat1 (512 threads cover 32 rows x 16 slots) ----
    {
        int row = tid >> 4, slot = tid & 15;   // slot == lo
        uint4 v = make_uint4(0u, 0u, 0u, 0u);
        if (row0 + row < N) v = ((const uint4*)(featb + (size_t)(row0 + row) * 64))[slot];
        if (BN) {
            unsigned int wz[4] = { v.x, v.y, v.z, v.w };
            unsigned int oz[4];
            #pragma unroll
            for (int k = 0; k < 4; ++k) {
                float tx = bf_lo(wz[k]), ty = bf_hi(wz[k]);
                tx = fmaxf(fmaf(bnA[k * 2], tx, bnC[k * 2]), 0.f);
                ty = fmaxf(fmaf(bnA[k * 2 + 1], ty, bnC[k * 2 + 1]), 0.f);
                oz[k] = ((unsigned int)f2bf_rne(ty) << 16) | f2bf_rne(tx);
            }
            v = make_uint4(oz[0], oz[1], oz[2], oz[3]);
        }
        int sp = slot ^ (row & 15);
        *(uint4*)(smem + (1 * 32 + row) * 256 + sp * 16) = v;
    }
    __syncthreads();

    // ---- phase 2: MFMA (wave wv = column tile ct) ----
    int lr = lane & 15, lk = lane >> 4;
    int ct = wv;
    f32x4 acc[2] = {};
    if (ct < NT) {
        for (int kk = 0; kk < 4; ++kk) {
            bf16x8 a[2][2];   // [rowtile][mat]
            int sp = (kk * 4 + lk) ^ lr;
            #pragma unroll
            for (int rt = 0; rt < 2; ++rt)
                #pragma unroll
                for (int mat = 0; mat < 2; ++mat)
                    a[rt][mat] = *(const bf16x8*)(smem + (mat * 32 + rt * 16 + lr) * 256 + sp * 16);
            int fo = ((ct * 4 + kk) * 64 + lane) * 8;
            #pragma unroll
            for (int mat = 0; mat < 2; ++mat) {
                bf16x8 bH = *(const bf16x8*)(pk + (size_t)(mat * 2 + 0) * NT * 2048 + fo);
                bf16x8 bL = *(const bf16x8*)(pk + (size_t)(mat * 2 + 1) * NT * 2048 + fo);
                #pragma unroll
                for (int rt = 0; rt < 2; ++rt) {
                    acc[rt] = __builtin_amdgcn_mfma_f32_16x16x32_bf16(a[rt][mat], bH, acc[rt], 0, 0, 0);
                    acc[rt] = __builtin_amdgcn_mfma_f32_16x16x32_bf16(a[rt][mat], bL, acc[rt], 0, 0, 0);
                }
            }
        }
    }

    // ---- phase 3: epilogue ----
    if constexpr (!SOFTMAX) {
        if (ct < NT) {
            int colj = ct * 16 + lr;
            float bv = bias[colj];
            #pragma unroll
            for (int rt = 0; rt < 2; ++rt) {
                #pragma unroll
                for (int r = 0; r < 4; ++r) {
                    int row = row0 + rt * 16 + lk * 4 + r;
                    if (row < N)
                        outh[(size_t)row * HDIM + colj] = f2bf_rne(acc[rt][r] + bv);
                }
            }
        }
    } else {
        __shared__ float ls[32][48];
        if (ct < NT) {
            int colj = ct * 16 + lr;
            float bv = (colj < FOUT) ? bias[colj] : 0.f;
            #pragma unroll
            for (int rt = 0; rt < 2; ++rt) {
                #pragma unroll
                for (int r = 0; r < 4; ++r) {
                    int row = rt * 16 + lk * 4 + r;
                    float val = acc[rt][r] + bv;
                    ls[row][colj] = (colj < FOUT) ? val : -INFINITY;
                }
            }
        }
        __syncthreads();
        #pragma unroll
        for (int rr = 0; rr < 4; ++rr) {
            int row = wv * 4 + rr;
            float v = (lane < 48) ? ls[row][lane] : -INFINITY;
            float m = v;
            #pragma unroll
            for (int o = 32; o; o >>= 1) m = fmaxf(m, __shfl_xor(m, o));
            float e = (lane < 48) ? expf(v - m) : 0.f;
            float s = e;
            #pragma unroll
            for (int o = 32; o; o >>= 1) s += __shfl_xor(s, o);
            int grow = row0 + row;
            if (grow < N && lane < FOUT)
                outf[(size_t)grow * FOUT + lane] = v - m - logf(s);
        }
    }
}

// ================= BN stats from bf16 plane =================
__global__ __launch_bounds__(256) void k_bnstats(const unsigned int* __restrict__ hb,
                                                 float* __restrict__ stats, int N) {
    __shared__ float l1[8 * HDIM];
    __shared__ float l2[8 * HDIM];
    int t = threadIdx.x;
    int cg = t & 31;
    int rs = t >> 5;
    float4 s1 = make_float4(0.f, 0.f, 0.f, 0.f);
    float4 s2 = make_float4(0.f, 0.f, 0.f, 0.f);
    for (int r = blockIdx.x * 8 + rs; r < N; r += gridDim.x * 8) {
        uint2 u = *(const uint2*)(hb + (size_t)r * 64 + cg * 2);
        float v0 = bf_lo(u.x), v1 = bf_hi(u.x), v2 = bf_lo(u.y), v3 = bf_hi(u.y);
        s1.x += v0; s1.y += v1; s1.z += v2; s1.w += v3;
        s2.x += v0 * v0; s2.y += v1 * v1; s2.z += v2 * v2; s2.w += v3 * v3;
    }
    *(float4*)&l1[rs * HDIM + cg * 4] = s1;
    *(float4*)&l2[rs * HDIM + cg * 4] = s2;
    __syncthreads();
    if (t < HDIM) {
        float a = 0.f;
        #pragma unroll
        for (int r = 0; r < 8; ++r) a += l1[r * HDIM + t];
        atomicAdd(&stats[t], a);
    } else {
        int j = t - HDIM;
        float a = 0.f;
        #pragma unroll
        for (int r = 0; r < 8; ++r) a += l2[r * HDIM + j];
        atomicAdd(&stats[HDIM + j], a);
    }
}

extern "C" void kernel_launch(void* const* d_in, const int* in_sizes, int n_in,
                              void* d_out, int out_size, void* d_ws, size_t ws_size,
                              hipStream_t stream) {
    const float* x   = (const float*)d_in[0];
    const int*   ei  = (const int*)d_in[1];
    const float* Wl0 = (const float*)d_in[2];
    const float* bl0 = (const float*)d_in[3];
    const float* Wr0 = (const float*)d_in[4];
    const float* g0  = (const float*)d_in[5];
    const float* b0  = (const float*)d_in[6];
    const float* Wl1 = (const float*)d_in[7];
    const float* bl1 = (const float*)d_in[8];
    const float* Wr1 = (const float*)d_in[9];
    const float* g1  = (const float*)d_in[10];
    const float* b1  = (const float*)d_in[11];
    const float* Wlo = (const float*)d_in[12];
    const float* blo = (const float*)d_in[13];
    const float* Wro = (const float*)d_in[14];

    int N = in_sizes[0] / HDIM;
    int E = in_sizes[1] / 2;
    int C = in_sizes[14] / HDIM;   // Wro is [128, C]
    float* out = (float*)d_out;
    float invN = 1.0f / (float)N;

    // ---- workspace layout (16B-aligned blocks) ----
    int*   col    = (int*)d_ws;                        // E
    int*   cnt    = col + E;                           // N
    int*   rowptr = cnt + N;                           // N+4
    int*   bsum   = rowptr + (N + 4);                  // 64
    float* stats0 = (float*)(bsum + 64);               // 256
    float* stats1 = stats0 + 256;                      // 256
    unsigned short* pk0 = (unsigned short*)(stats1 + 256);  // 65536
    unsigned short* pk1 = pk0 + 65536;                      // 65536
    unsigned short* pko = pk1 + 65536;                      // 24576
    unsigned int* fbf = (unsigned int*)(pko + 24576);       // N*64 bf16(x)
    unsigned int* hb0 = fbf + (size_t)N * 64;               // N*64 bf16 pre-BN h (layer 0)
    unsigned int* hb1 = hb0 + (size_t)N * 64;               // N*64 bf16 pre-BN h (layer 1)

    int nb = (N + SCAN_BLK - 1) / SCAN_BLK;
    size_t n2 = (size_t)N * 64;

    // ---- prep ----
    k_tobf<<<(int)((n2 + 255) / 256), 256, 0, stream>>>(x, fbf, n2, cnt, N);
    k_hist<<<(E + 255) / 256, 256, 0, stream>>>(ei, cnt, E);
    k_scan1<<<nb, 256, 0, stream>>>(cnt, rowptr, bsum, N);
    k_scan3<<<(N + 255) / 256, 256, 0, stream>>>(rowptr, bsum, N, E);
    k_fill<<<(E + 255) / 256, 256, 0, stream>>>(ei, rowptr, cnt, col, E);
    k_pack_all<<<dim3(64, 6), 256, 0, stream>>>(Wl0, Wr0, Wl1, Wr1, Wlo, Wro, pk0, pk1, pko, stats0, C);

    int mfma_blocks = (N + 31) / 32;

    // ---- layer 0 (no input BN) ----
    k_sage_fused<8, false, false><<<mfma_blocks, 512, 0, stream>>>(
        rowptr, col, fbf, nullptr, nullptr, nullptr, pk0, bl0,
        nullptr, (unsigned short*)hb0, N, HDIM, invN);
    k_bnstats<<<1024, 256, 0, stream>>>(hb0, stats0, N);

    // ---- layer 1 (BN(stats0) fused on input) ----
    k_sage_fused<8, true, false><<<mfma_blocks, 512, 0, stream>>>(
        rowptr, col, hb0, stats0, g0, b0, pk1, bl1,
        nullptr, (unsigned short*)hb1, N, HDIM, invN);
    k_bnstats<<<1024, 256, 0, stream>>>(hb1, stats1, N);

    // ---- output layer (BN(stats1) fused on input, log_softmax fused on output) ----
    k_sage_fused<3, true, true><<<mfma_blocks, 512, 0, stream>>>(
        rowptr, col, hb1, stats1, g1, b1, pko, blo,
        out, nullptr, N, C, invN);
}

// Round 13
// 254.430 us; speedup vs baseline: 1.1299x; 1.1299x over previous
//
#include <hip/hip_runtime.h>
#include <cstdint>

#define HDIM 128
#define EPSV 1e-5f
#define SCAN_BLK 1024

typedef short  short8 __attribute__((ext_vector_type(8)));
typedef __bf16 bf16x8 __attribute__((ext_vector_type(8)));
typedef float  f32x4  __attribute__((ext_vector_type(4)));
typedef float  f32x2  __attribute__((ext_vector_type(2)));

__device__ __forceinline__ unsigned short f2bf_rne(float x) {
    unsigned int u = __float_as_uint(x);
    return (unsigned short)((u + 0x7FFFu + ((u >> 16) & 1u)) >> 16);
}
__device__ __forceinline__ float bf_lo(unsigned int u) { return __uint_as_float(u << 16); }
__device__ __forceinline__ float bf_hi(unsigned int u) { return __uint_as_float(u & 0xFFFF0000u); }

// pack 4 f32 -> 4 fp8(e4m3) bytes in one uint
__device__ __forceinline__ unsigned int pk_fp8x4(float a, float b, float c, float d) {
    unsigned int u = __builtin_amdgcn_cvt_pk_fp8_f32(a, b, 0, false);
    u = __builtin_amdgcn_cvt_pk_fp8_f32(c, d, u, true);
    return u;
}

// ================= CSR build =================
__global__ void k_hist(const int* __restrict__ ei, int* __restrict__ cnt, int E) {
    int e = blockIdx.x * blockDim.x + threadIdx.x;
    if (e < E) atomicAdd(&cnt[ei[E + e]], 1);
}

__global__ __launch_bounds__(256) void k_scan1(const int* __restrict__ cnt,
                                               int* __restrict__ rowptr,
                                               int* __restrict__ bsum, int N) {
    __shared__ int lds[256];
    int b = blockIdx.x, t = threadIdx.x;
    int base = b * SCAN_BLK;
    int v[4]; int s = 0;
    #pragma unroll
    for (int c = 0; c < 4; ++c) { int i = base + t * 4 + c; v[c] = (i < N) ? cnt[i] : 0; s += v[c]; }
    lds[t] = s; __syncthreads();
    for (int off = 1; off < 256; off <<= 1) {
        int x = 0;
        if (t >= off) x = lds[t - off];
        __syncthreads();
        if (t >= off) lds[t] += x;
        __syncthreads();
    }
    int excl = (t > 0) ? lds[t - 1] : 0;
    if (t == 255) bsum[b] = lds[255];
    int run = excl;
    #pragma unroll
    for (int c = 0; c < 4; ++c) { int i = base + t * 4 + c; if (i < N) rowptr[i] = run; run += v[c]; }
}

__global__ void k_scan3(int* __restrict__ rowptr, const int* __restrict__ bsum, int N, int E) {
    int i = blockIdx.x * blockDim.x + threadIdx.x;
    if (i < N) {
        int nb = i / SCAN_BLK;
        int off = 0;
        for (int k = 0; k < nb; ++k) off += bsum[k];
        rowptr[i] += off;
    }
    if (i == 0) rowptr[N] = E;
}

__global__ void k_fill(const int* __restrict__ ei, const int* __restrict__ rowptr,
                       int* __restrict__ cnt, int* __restrict__ col, int E) {
    int e = blockIdx.x * blockDim.x + threadIdx.x;
    if (e < E) {
        int d = ei[E + e];
        int p = atomicSub(&cnt[d], 1) - 1;
        col[rowptr[d] + p] = ei[e];
    }
}

// ================= fp32 -> bf16 plane + fp8 plane (also zeroes cnt) =================
// thread handles 8 consecutive floats
__global__ void k_tobf(const float* __restrict__ src, unsigned int* __restrict__ dstb,
                       unsigned int* __restrict__ dst8, size_t n8,
                       int* __restrict__ cnt, int N) {
    size_t i = (size_t)blockIdx.x * blockDim.x + threadIdx.x;
    if (i < (size_t)N) cnt[i] = 0;
    if (i >= n8) return;
    float4 v0 = ((const float4*)src)[i * 2];
    float4 v1 = ((const float4*)src)[i * 2 + 1];
    uint4 ub;
    ub.x = ((unsigned int)f2bf_rne(v0.y) << 16) | f2bf_rne(v0.x);
    ub.y = ((unsigned int)f2bf_rne(v0.w) << 16) | f2bf_rne(v0.z);
    ub.z = ((unsigned int)f2bf_rne(v1.y) << 16) | f2bf_rne(v1.x);
    ub.w = ((unsigned int)f2bf_rne(v1.w) << 16) | f2bf_rne(v1.z);
    ((uint4*)dstb)[i] = ub;
    uint2 u8;
    u8.x = pk_fp8x4(v0.x, v0.y, v0.z, v0.w);
    u8.y = pk_fp8x4(v1.x, v1.y, v1.z, v1.w);
    ((uint2*)dst8)[i] = u8;
}

// ================= bf16 plane -> fp8 plane (single writer per plane) =================
__global__ void k_h2f8(const unsigned int* __restrict__ hb, unsigned int* __restrict__ f8, size_t n) {
    size_t i = (size_t)blockIdx.x * blockDim.x + threadIdx.x;
    if (i >= n) return;
    uint2 u = ((const uint2*)hb)[i];
    f8[i] = pk_fp8x4(bf_lo(u.x), bf_hi(u.x), bf_lo(u.y), bf_hi(u.y));
}

// ================= W pre-pack into MFMA B-fragment order (hi/lo split); zeroes stats =================
__global__ void k_pack_all(const float* __restrict__ Wl0, const float* __restrict__ Wr0,
                           const float* __restrict__ Wl1, const float* __restrict__ Wr1,
                           const float* __restrict__ Wlo, const float* __restrict__ Wro,
                           unsigned short* __restrict__ pk0, unsigned short* __restrict__ pk1,
                           unsigned short* __restrict__ pko, float* __restrict__ stats01, int C) {
    if (blockIdx.y == 0 && blockIdx.x == 0) {
        stats01[threadIdx.x] = 0.f;
        stats01[256 + threadIdx.x] = 0.f;
    }
    const float* W; unsigned short* WH; unsigned short* WL; int FOUT, NT;
    switch (blockIdx.y) {
        case 0:  W = Wl0; WH = pk0;          WL = pk0 + 16384; FOUT = 128; NT = 8; break;
        case 1:  W = Wr0; WH = pk0 + 32768;  WL = pk0 + 49152; FOUT = 128; NT = 8; break;
        case 2:  W = Wl1; WH = pk1;          WL = pk1 + 16384; FOUT = 128; NT = 8; break;
        case 3:  W = Wr1; WH = pk1 + 32768;  WL = pk1 + 49152; FOUT = 128; NT = 8; break;
        case 4:  W = Wlo; WH = pko;          WL = pko + 6144;  FOUT = C;   NT = 3; break;
        default: W = Wro; WH = pko + 12288;  WL = pko + 18432; FOUT = C;   NT = 3; break;
    }
    int tid = blockIdx.x * 256 + threadIdx.x;
    if (tid >= NT * 2048) return;
    int e = tid & 7, lane = (tid >> 3) & 63, kk = (tid >> 9) & 3, ct = tid >> 11;
    int j = ct * 16 + (lane & 15);
    int k = kk * 32 + (lane >> 4) * 8 + e;
    float v = (j < FOUT) ? W[k * FOUT + j] : 0.0f;
    unsigned short h = f2bf_rne(v);
    float hf = __uint_as_float((unsigned int)h << 16);
    unsigned short l = f2bf_rne(v - hf);
    WH[tid] = h; WL[tid] = l;
}

// ================= fully fused SAGE layer =================
// gather path reads fp8 plane (128B/row); self path reads bf16 plane; optional BN+relu on both.
template<int NT, bool BN, bool SOFTMAX>
__global__ __launch_bounds__(512) void k_sage_fused(
    const int* __restrict__ rowptr, const int* __restrict__ col,
    const unsigned int* __restrict__ featb,      // bf16 plane (self)
    const unsigned int* __restrict__ feat8,      // fp8 plane (gather)
    const float* __restrict__ stats, const float* __restrict__ gam, const float* __restrict__ bet,
    const unsigned short* __restrict__ pk, const float* __restrict__ bias,
    float* __restrict__ outf, unsigned short* __restrict__ outh,
    int N, int FOUT, float invN) {
    __shared__ __align__(16) char smem[16384];   // [mat][32 rows][16 slots * 16B]
    int tid = threadIdx.x;
    int row0 = blockIdx.x * 32;
    int lane = tid & 63;
    int wv = tid >> 6;            // 0..7
    int g4 = lane >> 4;           // edge group 0..3
    int lo = lane & 15;           // 8-col chunk

    // BN coefficients for this thread's 8 columns
    float bnA[8], bnC[8];
    if (BN) {
        #pragma unroll
        for (int c = 0; c < 8; ++c) {
            int j = lo * 8 + c;
            float mu = stats[j] * invN;
            float var = stats[HDIM + j] * invN - mu * mu;
            float aa = gam[j] * rsqrtf(var + EPSV);
            bnA[c] = aa; bnC[c] = bet[j] - mu * aa;
        }
    }

    // ---- phase 1a: gather (4 nodes per wave, stride-4 edges, fp8 uint2 loads) ----
    #pragma unroll
    for (int nn = 0; nn < 4; ++nn) {
        int row = wv * 4 + nn;
        int node = row0 + row;
        float a[8] = {0,0,0,0,0,0,0,0};
        int beg = 0, end = 0;
        if (node < N) { beg = rowptr[node]; end = rowptr[node + 1]; }
        for (int e = beg + g4; e < end; e += 4) {
            const uint2 v = *(const uint2*)(feat8 + (size_t)col[e] * 32 + lo * 2);
            f32x2 p0 = __builtin_amdgcn_cvt_pk_f32_fp8(v.x, false);
            f32x2 p1 = __builtin_amdgcn_cvt_pk_f32_fp8(v.x, true);
            f32x2 p2 = __builtin_amdgcn_cvt_pk_f32_fp8(v.y, false);
            f32x2 p3 = __builtin_amdgcn_cvt_pk_f32_fp8(v.y, true);
            float t[8] = { p0[0], p0[1], p1[0], p1[1], p2[0], p2[1], p3[0], p3[1] };
            if (BN) {
                #pragma unroll
                for (int c = 0; c < 8; ++c) t[c] = fmaxf(fmaf(bnA[c], t[c], bnC[c]), 0.f);
            }
            #pragma unroll
            for (int c = 0; c < 8; ++c) a[c] += t[c];
        }
        #pragma unroll
        for (int i = 0; i < 8; ++i) {
            a[i] += __shfl_xor(a[i], 16);
            a[i] += __shfl_xor(a[i], 32);
        }
        if (g4 == 0) {
            int deg = end - beg;
            float inv = (deg > 0) ? 1.0f / (float)deg : 0.0f;
            uint4 o;
            o.x = ((unsigned int)f2bf_rne(a[1] * inv) << 16) | f2bf_rne(a[0] * inv);
            o.y = ((unsigned int)f2bf_rne(a[3] * inv) << 16) | f2bf_rne(a[2] * inv);
            o.z = ((unsigned int)f2bf_rne(a[5] * inv) << 16) | f2bf_rne(a[4] * inv);
            o.w = ((unsigned int)f2bf_rne(a[7] * inv) << 16) | f2bf_rne(a[6] * inv);
            int sp = lo ^ (row & 15);
            *(uint4*)(smem + (0 * 32 + row) * 256 + sp * 16) = o;
        }
    }

    // ---- phase 1b: self features (bf16 plane) -> LDS mat1 ----
    {
        int row = tid >> 4, slot = tid & 15;
        uint4 v = make_uint4(0u, 0u, 0u, 0u);
        if (row0 + row < N) v = ((const uint4*)(featb + (size_t)(row0 + row) * 64))[slot];
        if (BN) {
            unsigned int wz[4] = { v.x, v.y, v.z, v.w };
            unsigned int oz[4];
            #pragma unroll
            for (int k = 0; k < 4; ++k) {
                float tx = bf_lo(wz[k]), ty = bf_hi(wz[k]);
                tx = fmaxf(fmaf(bnA[k * 2], tx, bnC[k * 2]), 0.f);
                ty = fmaxf(fmaf(bnA[k * 2 + 1], ty, bnC[k * 2 + 1]), 0.f);
                oz[k] = ((unsigned int)f2bf_rne(ty) << 16) | f2bf_rne(tx);
            }
            v = make_uint4(oz[0], oz[1], oz[2], oz[3]);
        }
        int sp = slot ^ (row & 15);
        *(uint4*)(smem + (1 * 32 + row) * 256 + sp * 16) = v;
    }
    __syncthreads();

    // ---- phase 2: MFMA (wave wv = column tile ct) ----
    int lr = lane & 15, lk = lane >> 4;
    int ct = wv;
    f32x4 acc[2] = {};
    if (ct < NT) {
        for (int kk = 0; kk < 4; ++kk) {
            bf16x8 a[2][2];   // [rowtile][mat]
            int sp = (kk * 4 + lk) ^ lr;
            #pragma unroll
            for (int rt = 0; rt < 2; ++rt)
                #pragma unroll
                for (int mat = 0; mat < 2; ++mat)
                    a[rt][mat] = *(const bf16x8*)(smem + (mat * 32 + rt * 16 + lr) * 256 + sp * 16);
            int fo = ((ct * 4 + kk) * 64 + lane) * 8;
            #pragma unroll
            for (int mat = 0; mat < 2; ++mat) {
                bf16x8 bH = *(const bf16x8*)(pk + (size_t)(mat * 2 + 0) * NT * 2048 + fo);
                bf16x8 bL = *(const bf16x8*)(pk + (size_t)(mat * 2 + 1) * NT * 2048 + fo);
                #pragma unroll
                for (int rt = 0; rt < 2; ++rt) {
                    acc[rt] = __builtin_amdgcn_mfma_f32_16x16x32_bf16(a[rt][mat], bH, acc[rt], 0, 0, 0);
                    acc[rt] = __builtin_amdgcn_mfma_f32_16x16x32_bf16(a[rt][mat], bL, acc[rt], 0, 0, 0);
                }
            }
        }
    }

    // ---- phase 3: epilogue ----
    if constexpr (!SOFTMAX) {
        if (ct < NT) {
            int colj = ct * 16 + lr;
            float bv = bias[colj];
            #pragma unroll
            for (int rt = 0; rt < 2; ++rt) {
                #pragma unroll
                for (int r = 0; r < 4; ++r) {
                    int row = row0 + rt * 16 + lk * 4 + r;
                    if (row < N)
                        outh[(size_t)row * HDIM + colj] = f2bf_rne(acc[rt][r] + bv);
                }
            }
        }
    } else {
        __shared__ float ls[32][48];
        if (ct < NT) {
            int colj = ct * 16 + lr;
            float bv = (colj < FOUT) ? bias[colj] : 0.f;
            #pragma unroll
            for (int rt = 0; rt < 2; ++rt) {
                #pragma unroll
                for (int r = 0; r < 4; ++r) {
                    int row = rt * 16 + lk * 4 + r;
                    float val = acc[rt][r] + bv;
                    ls[row][colj] = (colj < FOUT) ? val : -INFINITY;
                }
            }
        }
        __syncthreads();
        #pragma unroll
        for (int rr = 0; rr < 4; ++rr) {
            int row = wv * 4 + rr;
            float v = (lane < 48) ? ls[row][lane] : -INFINITY;
            float m = v;
            #pragma unroll
            for (int o = 32; o; o >>= 1) m = fmaxf(m, __shfl_xor(m, o));
            float e = (lane < 48) ? expf(v - m) : 0.f;
            float s = e;
            #pragma unroll
            for (int o = 32; o; o >>= 1) s += __shfl_xor(s, o);
            int grow = row0 + row;
            if (grow < N && lane < FOUT)
                outf[(size_t)grow * FOUT + lane] = v - m - logf(s);
        }
    }
}

// ================= BN stats from bf16 plane (pure stats, 1 atomic/col/block) =================
__global__ __launch_bounds__(256) void k_bnstats(const unsigned int* __restrict__ hb,
                                                 float* __restrict__ stats, int N) {
    __shared__ float l1[8 * HDIM];
    __shared__ float l2[8 * HDIM];
    int t = threadIdx.x;
    int cg = t & 31;
    int rs = t >> 5;
    float4 s1 = make_float4(0.f, 0.f, 0.f, 0.f);
    float4 s2 = make_float4(0.f, 0.f, 0.f, 0.f);
    for (int r = blockIdx.x * 8 + rs; r < N; r += gridDim.x * 8) {
        uint2 u = *(const uint2*)(hb + (size_t)r * 64 + cg * 2);
        float v0 = bf_lo(u.x), v1 = bf_hi(u.x), v2 = bf_lo(u.y), v3 = bf_hi(u.y);
        s1.x += v0; s1.y += v1; s1.z += v2; s1.w += v3;
        s2.x += v0 * v0; s2.y += v1 * v1; s2.z += v2 * v2; s2.w += v3 * v3;
    }
    *(float4*)&l1[rs * HDIM + cg * 4] = s1;
    *(float4*)&l2[rs * HDIM + cg * 4] = s2;
    __syncthreads();
    if (t < HDIM) {
        float a = 0.f;
        #pragma unroll
        for (int r = 0; r < 8; ++r) a += l1[r * HDIM + t];
        atomicAdd(&stats[t], a);
    } else {
        int j = t - HDIM;
        float a = 0.f;
        #pragma unroll
        for (int r = 0; r < 8; ++r) a += l2[r * HDIM + j];
        atomicAdd(&stats[HDIM + j], a);
    }
}

extern "C" void kernel_launch(void* const* d_in, const int* in_sizes, int n_in,
                              void* d_out, int out_size, void* d_ws, size_t ws_size,
                              hipStream_t stream) {
    const float* x   = (const float*)d_in[0];
    const int*   ei  = (const int*)d_in[1];
    const float* Wl0 = (const float*)d_in[2];
    const float* bl0 = (const float*)d_in[3];
    const float* Wr0 = (const float*)d_in[4];
    const float* g0  = (const float*)d_in[5];
    const float* b0  = (const float*)d_in[6];
    const float* Wl1 = (const float*)d_in[7];
    const float* bl1 = (const float*)d_in[8];
    const float* Wr1 = (const float*)d_in[9];
    const float* g1  = (const float*)d_in[10];
    const float* b1  = (const float*)d_in[11];
    const float* Wlo = (const float*)d_in[12];
    const float* blo = (const float*)d_in[13];
    const float* Wro = (const float*)d_in[14];

    int N = in_sizes[0] / HDIM;
    int E = in_sizes[1] / 2;
    int C = in_sizes[14] / HDIM;   // Wro is [128, C]
    float* out = (float*)d_out;
    float invN = 1.0f / (float)N;

    // ---- workspace layout (16B-aligned blocks; every buffer has ONE writer kernel) ----
    int*   col    = (int*)d_ws;                        // E
    int*   cnt    = col + E;                           // N
    int*   rowptr = cnt + N;                           // N+4
    int*   bsum   = rowptr + (N + 4);                  // 64
    float* stats0 = (float*)(bsum + 64);               // 256
    float* stats1 = stats0 + 256;                      // 256
    unsigned short* pk0 = (unsigned short*)(stats1 + 256);  // 65536
    unsigned short* pk1 = pk0 + 65536;                      // 65536
    unsigned short* pko = pk1 + 65536;                      // 24576
    unsigned int* fbf = (unsigned int*)(pko + 24576);       // N*64 bf16(x)
    unsigned int* hb0 = fbf + (size_t)N * 64;               // N*64 bf16 pre-BN h0
    unsigned int* hb1 = hb0 + (size_t)N * 64;               // N*64 bf16 pre-BN h1
    unsigned int* f8x = hb1 + (size_t)N * 64;               // N*32 fp8(x)
    unsigned int* f80 = f8x + (size_t)N * 32;               // N*32 fp8(h0)
    unsigned int* f81 = f80 + (size_t)N * 32;               // N*32 fp8(h1)

    int nb = (N + SCAN_BLK - 1) / SCAN_BLK;
    size_t n8 = (size_t)N * 16;    // k_tobf threads (8 floats each)
    size_t nc = (size_t)N * 32;    // k_h2f8 threads (1 uint each)

    // ---- prep ----
    k_tobf<<<(int)((n8 + 255) / 256), 256, 0, stream>>>(x, fbf, f8x, n8, cnt, N);
    k_hist<<<(E + 255) / 256, 256, 0, stream>>>(ei, cnt, E);
    k_scan1<<<nb, 256, 0, stream>>>(cnt, rowptr, bsum, N);
    k_scan3<<<(N + 255) / 256, 256, 0, stream>>>(rowptr, bsum, N, E);
    k_fill<<<(E + 255) / 256, 256, 0, stream>>>(ei, rowptr, cnt, col, E);
    k_pack_all<<<dim3(64, 6), 256, 0, stream>>>(Wl0, Wr0, Wl1, Wr1, Wlo, Wro, pk0, pk1, pko, stats0, C);

    int mfma_blocks = (N + 31) / 32;
    int h2f8_blocks = (int)((nc + 255) / 256);

    // ---- layer 0 (no input BN): gather fp8(x), self bf16(x) ----
    k_sage_fused<8, false, false><<<mfma_blocks, 512, 0, stream>>>(
        rowptr, col, fbf, f8x, nullptr, nullptr, nullptr, pk0, bl0,
        nullptr, (unsigned short*)hb0, N, HDIM, invN);
    k_bnstats<<<512, 256, 0, stream>>>(hb0, stats0, N);
    k_h2f8<<<h2f8_blocks, 256, 0, stream>>>(hb0, f80, nc);

    // ---- layer 1: gather fp8(h0)+BN, self bf16(h0)+BN ----
    k_sage_fused<8, true, false><<<mfma_blocks, 512, 0, stream>>>(
        rowptr, col, hb0, f80, stats0, g0, b0, pk1, bl1,
        nullptr, (unsigned short*)hb1, N, HDIM, invN);
    k_bnstats<<<512, 256, 0, stream>>>(hb1, stats1, N);
    k_h2f8<<<h2f8_blocks, 256, 0, stream>>>(hb1, f81, nc);

    // ---- output layer: gather fp8(h1)+BN, self bf16(h1)+BN, fused log_softmax ----
    k_sage_fused<3, true, true><<<mfma_blocks, 512, 0, stream>>>(
        rowptr, col, hb1, f81, stats1, g1, b1, pko, blo,
        out, nullptr, N, C, invN);
}

// Round 15
// 253.938 us; speedup vs baseline: 1.1321x; 1.0019x over previous
//
#include <hip/hip_runtime.h>
#include <cstdint>

#define HDIM 128
#define EPSV 1e-5f
#define SCAN_BLK 1024

typedef short  short8 __attribute__((ext_vector_type(8)));
typedef __bf16 bf16x8 __attribute__((ext_vector_type(8)));
typedef float  f32x4  __attribute__((ext_vector_type(4)));
typedef float  f32x2  __attribute__((ext_vector_type(2)));

__device__ __forceinline__ unsigned short f2bf_rne(float x) {
    unsigned int u = __float_as_uint(x);
    return (unsigned short)((u + 0x7FFFu + ((u >> 16) & 1u)) >> 16);
}
__device__ __forceinline__ float bf_lo(unsigned int u) { return __uint_as_float(u << 16); }
__device__ __forceinline__ float bf_hi(unsigned int u) { return __uint_as_float(u & 0xFFFF0000u); }

// pack 4 f32 -> 4 fp8(e4m3) bytes in one uint
__device__ __forceinline__ unsigned int pk_fp8x4(float a, float b, float c, float d) {
    unsigned int u = __builtin_amdgcn_cvt_pk_fp8_f32(a, b, 0, false);
    u = __builtin_amdgcn_cvt_pk_fp8_f32(c, d, u, true);
    return u;
}

// ================= CSR build =================
__global__ void k_hist(const int* __restrict__ ei, int* __restrict__ cnt, int E) {
    int e = blockIdx.x * blockDim.x + threadIdx.x;
    if (e < E) atomicAdd(&cnt[ei[E + e]], 1);
}

__global__ __launch_bounds__(256) void k_scan1(const int* __restrict__ cnt,
                                               int* __restrict__ rowptr,
                                               int* __restrict__ bsum, int N) {
    __shared__ int lds[256];
    int b = blockIdx.x, t = threadIdx.x;
    int base = b * SCAN_BLK;
    int v[4]; int s = 0;
    #pragma unroll
    for (int c = 0; c < 4; ++c) { int i = base + t * 4 + c; v[c] = (i < N) ? cnt[i] : 0; s += v[c]; }
    lds[t] = s; __syncthreads();
    for (int off = 1; off < 256; off <<= 1) {
        int x = 0;
        if (t >= off) x = lds[t - off];
        __syncthreads();
        if (t >= off) lds[t] += x;
        __syncthreads();
    }
    int excl = (t > 0) ? lds[t - 1] : 0;
    if (t == 255) bsum[b] = lds[255];
    int run = excl;
    #pragma unroll
    for (int c = 0; c < 4; ++c) { int i = base + t * 4 + c; if (i < N) rowptr[i] = run; run += v[c]; }
}

__global__ void k_scan3(int* __restrict__ rowptr, const int* __restrict__ bsum, int N, int E) {
    int i = blockIdx.x * blockDim.x + threadIdx.x;
    if (i < N) {
        int nb = i / SCAN_BLK;
        int off = 0;
        for (int k = 0; k < nb; ++k) off += bsum[k];
        rowptr[i] += off;
    }
    if (i == 0) rowptr[N] = E;
}

__global__ void k_fill(const int* __restrict__ ei, const int* __restrict__ rowptr,
                       int* __restrict__ cnt, int* __restrict__ col, int E) {
    int e = blockIdx.x * blockDim.x + threadIdx.x;
    if (e < E) {
        int d = ei[E + e];
        int p = atomicSub(&cnt[d], 1) - 1;
        col[rowptr[d] + p] = ei[e];
    }
}

// ================= fp32 -> bf16 plane + fp8 plane (also zeroes cnt) =================
// thread handles 8 consecutive floats
__global__ void k_tobf(const float* __restrict__ src, unsigned int* __restrict__ dstb,
                       unsigned int* __restrict__ dst8, size_t n8,
                       int* __restrict__ cnt, int N) {
    size_t i = (size_t)blockIdx.x * blockDim.x + threadIdx.x;
    if (i < (size_t)N) cnt[i] = 0;
    if (i >= n8) return;
    float4 v0 = ((const float4*)src)[i * 2];
    float4 v1 = ((const float4*)src)[i * 2 + 1];
    uint4 ub;
    ub.x = ((unsigned int)f2bf_rne(v0.y) << 16) | f2bf_rne(v0.x);
    ub.y = ((unsigned int)f2bf_rne(v0.w) << 16) | f2bf_rne(v0.z);
    ub.z = ((unsigned int)f2bf_rne(v1.y) << 16) | f2bf_rne(v1.x);
    ub.w = ((unsigned int)f2bf_rne(v1.w) << 16) | f2bf_rne(v1.z);
    ((uint4*)dstb)[i] = ub;
    uint2 u8;
    u8.x = pk_fp8x4(v0.x, v0.y, v0.z, v0.w);
    u8.y = pk_fp8x4(v1.x, v1.y, v1.z, v1.w);
    ((uint2*)dst8)[i] = u8;
}

// ================= bf16 plane -> fp8 plane (single writer per plane) =================
__global__ void k_h2f8(const unsigned int* __restrict__ hb, unsigned int* __restrict__ f8, size_t n) {
    size_t i = (size_t)blockIdx.x * blockDim.x + threadIdx.x;
    if (i >= n) return;
    uint2 u = ((const uint2*)hb)[i];
    f8[i] = pk_fp8x4(bf_lo(u.x), bf_hi(u.x), bf_lo(u.y), bf_hi(u.y));
}

// ================= W pre-pack into MFMA B-fragment order (hi/lo split); zeroes stats =================
__global__ void k_pack_all(const float* __restrict__ Wl0, const float* __restrict__ Wr0,
                           const float* __restrict__ Wl1, const float* __restrict__ Wr1,
                           const float* __restrict__ Wlo, const float* __restrict__ Wro,
                           unsigned short* __restrict__ pk0, unsigned short* __restrict__ pk1,
                           unsigned short* __restrict__ pko, float* __restrict__ stats01, int C) {
    if (blockIdx.y == 0 && blockIdx.x == 0) {
        stats01[threadIdx.x] = 0.f;
        stats01[256 + threadIdx.x] = 0.f;
    }
    const float* W; unsigned short* WH; unsigned short* WL; int FOUT, NT;
    switch (blockIdx.y) {
        case 0:  W = Wl0; WH = pk0;          WL = pk0 + 16384; FOUT = 128; NT = 8; break;
        case 1:  W = Wr0; WH = pk0 + 32768;  WL = pk0 + 49152; FOUT = 128; NT = 8; break;
        case 2:  W = Wl1; WH = pk1;          WL = pk1 + 16384; FOUT = 128; NT = 8; break;
        case 3:  W = Wr1; WH = pk1 + 32768;  WL = pk1 + 49152; FOUT = 128; NT = 8; break;
        case 4:  W = Wlo; WH = pko;          WL = pko + 6144;  FOUT = C;   NT = 3; break;
        default: W = Wro; WH = pko + 12288;  WL = pko + 18432; FOUT = C;   NT = 3; break;
    }
    int tid = blockIdx.x * 256 + threadIdx.x;
    if (tid >= NT * 2048) return;
    int e = tid & 7, lane = (tid >> 3) & 63, kk = (tid >> 9) & 3, ct = tid >> 11;
    int j = ct * 16 + (lane & 15);
    int k = kk * 32 + (lane >> 4) * 8 + e;
    float v = (j < FOUT) ? W[k * FOUT + j] : 0.0f;
    unsigned short h = f2bf_rne(v);
    float hf = __uint_as_float((unsigned int)h << 16);
    unsigned short l = f2bf_rne(v - hf);
    WH[tid] = h; WL[tid] = l;
}

// ================= fully fused SAGE layer =================
// gather path reads fp8 plane (128B/row); self path reads bf16 plane; optional BN+relu on both.
template<int NT, bool BN, bool SOFTMAX>
__global__ __launch_bounds__(512) void k_sage_fused(
    const int* __restrict__ rowptr, const int* __restrict__ col,
    const unsigned int* __restrict__ featb,      // bf16 plane (self)
    const unsigned int* __restrict__ feat8,      // fp8 plane (gather)
    const float* __restrict__ stats, const float* __restrict__ gam, const float* __restrict__ bet,
    const unsigned short* __restrict__ pk, const float* __restrict__ bias,
    float* __restrict__ outf, unsigned short* __restrict__ outh,
    int N, int FOUT, float invN) {
    __shared__ __align__(16) char smem[16384];   // [mat][32 rows][16 slots * 16B]
    int tid = threadIdx.x;
    int row0 = blockIdx.x * 32;
    int lane = tid & 63;
    int wv = tid >> 6;            // 0..7
    int g4 = lane >> 4;           // edge group 0..3
    int lo = lane & 15;           // 8-col chunk

    // BN coefficients for this thread's 8 columns
    float bnA[8], bnC[8];
    if (BN) {
        #pragma unroll
        for (int c = 0; c < 8; ++c) {
            int j = lo * 8 + c;
            float mu = stats[j] * invN;
            float var = stats[HDIM + j] * invN - mu * mu;
            float aa = gam[j] * rsqrtf(var + EPSV);
            bnA[c] = aa; bnC[c] = bet[j] - mu * aa;
        }
    }

    // ---- phase 1a: gather (4 nodes per wave, stride-4 edges, fp8 uint2 loads) ----
    #pragma unroll
    for (int nn = 0; nn < 4; ++nn) {
        int row = wv * 4 + nn;
        int node = row0 + row;
        float a[8] = {0,0,0,0,0,0,0,0};
        int beg = 0, end = 0;
        if (node < N) { beg = rowptr[node]; end = rowptr[node + 1]; }
        for (int e = beg + g4; e < end; e += 4) {
            const uint2 v = *(const uint2*)(feat8 + (size_t)col[e] * 32 + lo * 2);
            f32x2 p0 = __builtin_amdgcn_cvt_pk_f32_fp8(v.x, false);
            f32x2 p1 = __builtin_amdgcn_cvt_pk_f32_fp8(v.x, true);
            f32x2 p2 = __builtin_amdgcn_cvt_pk_f32_fp8(v.y, false);
            f32x2 p3 = __builtin_amdgcn_cvt_pk_f32_fp8(v.y, true);
            float t[8] = { p0[0], p0[1], p1[0], p1[1], p2[0], p2[1], p3[0], p3[1] };
            if (BN) {
                #pragma unroll
                for (int c = 0; c < 8; ++c) t[c] = fmaxf(fmaf(bnA[c], t[c], bnC[c]), 0.f);
            }
            #pragma unroll
            for (int c = 0; c < 8; ++c) a[c] += t[c];
        }
        #pragma unroll
        for (int i = 0; i < 8; ++i) {
            a[i] += __shfl_xor(a[i], 16);
            a[i] += __shfl_xor(a[i], 32);
        }
        if (g4 == 0) {
            int deg = end - beg;
            float inv = (deg > 0) ? 1.0f / (float)deg : 0.0f;
            uint4 o;
            o.x = ((unsigned int)f2bf_rne(a[1] * inv) << 16) | f2bf_rne(a[0] * inv);
            o.y = ((unsigned int)f2bf_rne(a[3] * inv) << 16) | f2bf_rne(a[2] * inv);
            o.z = ((unsigned int)f2bf_rne(a[5] * inv) << 16) | f2bf_rne(a[4] * inv);
            o.w = ((unsigned int)f2bf_rne(a[7] * inv) << 16) | f2bf_rne(a[6] * inv);
            int sp = lo ^ (row & 15);
            *(uint4*)(smem + (0 * 32 + row) * 256 + sp * 16) = o;
        }
    }

    // ---- phase 1b: self features (bf16 plane) -> LDS mat1 ----
    {
        int row = tid >> 4, slot = tid & 15;
        uint4 v = make_uint4(0u, 0u, 0u, 0u);
        if (row0 + row < N) v = ((const uint4*)(featb + (size_t)(row0 + row) * 64))[slot];
        if (BN) {
            unsigned int wz[4] = { v.x, v.y, v.z, v.w };
            unsigned int oz[4];
            #pragma unroll
            for (int k = 0; k < 4; ++k) {
                float tx = bf_lo(wz[k]), ty = bf_hi(wz[k]);
                tx = fmaxf(fmaf(bnA[k * 2], tx, bnC[k * 2]), 0.f);
                ty = fmaxf(fmaf(bnA[k * 2 + 1], ty, bnC[k * 2 + 1]), 0.f);
                oz[k] = ((unsigned int)f2bf_rne(ty) << 16) | f2bf_rne(tx);
            }
            v = make_uint4(oz[0], oz[1], oz[2], oz[3]);
        }
        int sp = slot ^ (row & 15);
        *(uint4*)(smem + (1 * 32 + row) * 256 + sp * 16) = v;
    }
    __syncthreads();

    // ---- phase 2: MFMA (wave wv = column tile ct) ----
    int lr = lane & 15, lk = lane >> 4;
    int ct = wv;
    f32x4 acc[2] = {};
    if (ct < NT) {
        for (int kk = 0; kk < 4; ++kk) {
            bf16x8 a[2][2];   // [rowtile][mat]
            int sp = (kk * 4 + lk) ^ lr;
            #pragma unroll
            for (int rt = 0; rt < 2; ++rt)
                #pragma unroll
                for (int mat = 0; mat < 2; ++mat)
                    a[rt][mat] = *(const bf16x8*)(smem + (mat * 32 + rt * 16 + lr) * 256 + sp * 16);
            int fo = ((ct * 4 + kk) * 64 + lane) * 8;
            #pragma unroll
            for (int mat = 0; mat < 2; ++mat) {
                bf16x8 bH = *(const bf16x8*)(pk + (size_t)(mat * 2 + 0) * NT * 2048 + fo);
                bf16x8 bL = *(const bf16x8*)(pk + (size_t)(mat * 2 + 1) * NT * 2048 + fo);
                #pragma unroll
                for (int rt = 0; rt < 2; ++rt) {
                    acc[rt] = __builtin_amdgcn_mfma_f32_16x16x32_bf16(a[rt][mat], bH, acc[rt], 0, 0, 0);
                    acc[rt] = __builtin_amdgcn_mfma_f32_16x16x32_bf16(a[rt][mat], bL, acc[rt], 0, 0, 0);
                }
            }
        }
    }

    // ---- phase 3: epilogue ----
    if constexpr (!SOFTMAX) {
        if (ct < NT) {
            int colj = ct * 16 + lr;
            float bv = bias[colj];
            #pragma unroll
            for (int rt = 0; rt < 2; ++rt) {
                #pragma unroll
                for (int r = 0; r < 4; ++r) {
                    int row = row0 + rt * 16 + lk * 4 + r;
                    if (row < N)
                        outh[(size_t)row * HDIM + colj] = f2bf_rne(acc[rt][r] + bv);
                }
            }
        }
    } else {
        __shared__ float ls[32][48];
        if (ct < NT) {
            int colj = ct * 16 + lr;
            float bv = (colj < FOUT) ? bias[colj] : 0.f;
            #pragma unroll
            for (int rt = 0; rt < 2; ++rt) {
                #pragma unroll
                for (int r = 0; r < 4; ++r) {
                    int row = rt * 16 + lk * 4 + r;
                    float val = acc[rt][r] + bv;
                    ls[row][colj] = (colj < FOUT) ? val : -INFINITY;
                }
            }
        }
        __syncthreads();
        #pragma unroll
        for (int rr = 0; rr < 4; ++rr) {
            int row = wv * 4 + rr;
            float v = (lane < 48) ? ls[row][lane] : -INFINITY;
            float m = v;
            #pragma unroll
            for (int o = 32; o; o >>= 1) m = fmaxf(m, __shfl_xor(m, o));
            float e = (lane < 48) ? expf(v - m) : 0.f;
            float s = e;
            #pragma unroll
            for (int o = 32; o; o >>= 1) s += __shfl_xor(s, o);
            int grow = row0 + row;
            if (grow < N && lane < FOUT)
                outf[(size_t)grow * FOUT + lane] = v - m - logf(s);
        }
    }
}

// ================= BN stats from bf16 plane (pure stats, 1 atomic/col/block) =================
__global__ __launch_bounds__(256) void k_bnstats(const unsigned int* __restrict__ hb,
                                                 float* __restrict__ stats, int N) {
    __shared__ float l1[8 * HDIM];
    __shared__ float l2[8 * HDIM];
    int t = threadIdx.x;
    int cg = t & 31;
    int rs = t >> 5;
    float4 s1 = make_float4(0.f, 0.f, 0.f, 0.f);
    float4 s2 = make_float4(0.f, 0.f, 0.f, 0.f);
    for (int r = blockIdx.x * 8 + rs; r < N; r += gridDim.x * 8) {
        uint2 u = *(const uint2*)(hb + (size_t)r * 64 + cg * 2);
        float v0 = bf_lo(u.x), v1 = bf_hi(u.x), v2 = bf_lo(u.y), v3 = bf_hi(u.y);
        s1.x += v0; s1.y += v1; s1.z += v2; s1.w += v3;
        s2.x += v0 * v0; s2.y += v1 * v1; s2.z += v2 * v2; s2.w += v3 * v3;
    }
    *(float4*)&l1[rs * HDIM + cg * 4] = s1;
    *(float4*)&l2[rs * HDIM + cg * 4] = s2;
    __syncthreads();
    if (t < HDIM) {
        float a = 0.f;
        #pragma unroll
        for (int r = 0; r < 8; ++r) a += l1[r * HDIM + t];
        atomicAdd(&stats[t], a);
    } else {
        int j = t - HDIM;
        float a = 0.f;
        #pragma unroll
        for (int r = 0; r < 8; ++r) a += l2[r * HDIM + j];
        atomicAdd(&stats[HDIM + j], a);
    }
}

extern "C" void kernel_launch(void* const* d_in, const int* in_sizes, int n_in,
                              void* d_out, int out_size, void* d_ws, size_t ws_size,
                              hipStream_t stream) {
    const float* x   = (const float*)d_in[0];
    const int*   ei  = (const int*)d_in[1];
    const float* Wl0 = (const float*)d_in[2];
    const float* bl0 = (const float*)d_in[3];
    const float* Wr0 = (const float*)d_in[4];
    const float* g0  = (const float*)d_in[5];
    const float* b0  = (const float*)d_in[6];
    const float* Wl1 = (const float*)d_in[7];
    const float* bl1 = (const float*)d_in[8];
    const float* Wr1 = (const float*)d_in[9];
    const float* g1  = (const float*)d_in[10];
    const float* b1  = (const float*)d_in[11];
    const float* Wlo = (const float*)d_in[12];
    const float* blo = (const float*)d_in[13];
    const float* Wro = (const float*)d_in[14];

    int N = in_sizes[0] / HDIM;
    int E = in_sizes[1] / 2;
    int C = in_sizes[14] / HDIM;   // Wro is [128, C]
    float* out = (float*)d_out;
    float invN = 1.0f / (float)N;

    // ---- workspace layout (16B-aligned blocks; every buffer has ONE writer kernel) ----
    int*   col    = (int*)d_ws;                        // E
    int*   cnt    = col + E;                           // N
    int*   rowptr = cnt + N;                           // N+4
    int*   bsum   = rowptr + (N + 4);                  // 64
    float* stats0 = (float*)(bsum + 64);               // 256
    float* stats1 = stats0 + 256;                      // 256
    unsigned short* pk0 = (unsigned short*)(stats1 + 256);  // 65536
    unsigned short* pk1 = pk0 + 65536;                      // 65536
    unsigned short* pko = pk1 + 65536;                      // 24576
    unsigned int* fbf = (unsigned int*)(pko + 24576);       // N*64 bf16(x)
    unsigned int* hb0 = fbf + (size_t)N * 64;               // N*64 bf16 pre-BN h0
    unsigned int* hb1 = hb0 + (size_t)N * 64;               // N*64 bf16 pre-BN h1
    unsigned int* f8x = hb1 + (size_t)N * 64;               // N*32 fp8(x)
    unsigned int* f80 = f8x + (size_t)N * 32;               // N*32 fp8(h0)
    unsigned int* f81 = f80 + (size_t)N * 32;               // N*32 fp8(h1)

    int nb = (N + SCAN_BLK - 1) / SCAN_BLK;
    size_t n8 = (size_t)N * 16;    // k_tobf threads (8 floats each)
    size_t nc = (size_t)N * 32;    // k_h2f8 threads (1 uint each)

    // ---- prep ----
    k_tobf<<<(int)((n8 + 255) / 256), 256, 0, stream>>>(x, fbf, f8x, n8, cnt, N);
    k_hist<<<(E + 255) / 256, 256, 0, stream>>>(ei, cnt, E);
    k_scan1<<<nb, 256, 0, stream>>>(cnt, rowptr, bsum, N);
    k_scan3<<<(N + 255) / 256, 256, 0, stream>>>(rowptr, bsum, N, E);
    k_fill<<<(E + 255) / 256, 256, 0, stream>>>(ei, rowptr, cnt, col, E);
    k_pack_all<<<dim3(64, 6), 256, 0, stream>>>(Wl0, Wr0, Wl1, Wr1, Wlo, Wro, pk0, pk1, pko, stats0, C);

    int mfma_blocks = (N + 31) / 32;
    int h2f8_blocks = (int)((nc + 255) / 256);

    // ---- layer 0 (no input BN): gather fp8(x), self bf16(x) ----
    k_sage_fused<8, false, false><<<mfma_blocks, 512, 0, stream>>>(
        rowptr, col, fbf, f8x, nullptr, nullptr, nullptr, pk0, bl0,
        nullptr, (unsigned short*)hb0, N, HDIM, invN);
    k_bnstats<<<512, 256, 0, stream>>>(hb0, stats0, N);
    k_h2f8<<<h2f8_blocks, 256, 0, stream>>>(hb0, f80, nc);

    // ---- layer 1: gather fp8(h0)+BN, self bf16(h0)+BN ----
    k_sage_fused<8, true, false><<<mfma_blocks, 512, 0, stream>>>(
        rowptr, col, hb0, f80, stats0, g0, b0, pk1, bl1,
        nullptr, (unsigned short*)hb1, N, HDIM, invN);
    k_bnstats<<<512, 256, 0, stream>>>(hb1, stats1, N);
    k_h2f8<<<h2f8_blocks, 256, 0, stream>>>(hb1, f81, nc);

    // ---- output layer: gather fp8(h1)+BN, self bf16(h1)+BN, fused log_softmax ----
    k_sage_fused<3, true, true><<<mfma_blocks, 512, 0, stream>>>(
        rowptr, col, hb1, f81, stats1, g1, b1, pko, blo,
        out, nullptr, N, C, invN);
}